// Round 8
// baseline (340.780 us; speedup 1.0000x reference)
//
#include <hip/hip_runtime.h>
#include <hip/hip_bf16.h>

#define LEAKY_ATT 0.2f
#define LEAKY_ACT 0.01f
#define BSHIFT 8
#define CH 4096

typedef __attribute__((ext_vector_type(8))) short bf16x8;
typedef __attribute__((ext_vector_type(4))) float f32x4;

__device__ __forceinline__ float lrelu(float x, float s) { return fmaxf(x, s * x); }

__device__ __forceinline__ uint f2bf(float f) {
  __hip_bfloat16 h = __float2bfloat16(f);  // RTNE
  return (uint)*reinterpret_cast<ushort*>(&h);
}

__device__ __forceinline__ float bf_lo(uint q) { return __uint_as_float(q << 16); }
__device__ __forceinline__ float bf_hi(uint q) { return __uint_as_float(q & 0xffff0000u); }

// ============================ CSR build: two-level counting sort ============================
__global__ __launch_bounds__(256) void k_bhist(const int* __restrict__ dst, int e, int nb,
                                               int* __restrict__ bcnt) {
  __shared__ int cnt[512];
  for (int i = threadIdx.x; i < 512; i += 256) cnt[i] = 0;
  __syncthreads();
  for (int i = blockIdx.x * 256 + threadIdx.x; i < e; i += gridDim.x * 256)
    atomicAdd(&cnt[dst[i] >> BSHIFT], 1);
  __syncthreads();
  for (int i = threadIdx.x; i < nb; i += 256)
    if (cnt[i]) atomicAdd(&bcnt[i], cnt[i]);
}

__global__ __launch_bounds__(512) void k_bscan(const int* __restrict__ bcnt, int nb,
                                               int* __restrict__ bbase, int* __restrict__ bcur) {
  __shared__ int sh[512];
  int t = threadIdx.x;
  int orig = (t < nb) ? bcnt[t] : 0;
  sh[t] = orig;
  __syncthreads();
  for (int off = 1; off < 512; off <<= 1) {
    int v = (t >= off) ? sh[t - off] : 0;
    __syncthreads();
    sh[t] += v;
    __syncthreads();
  }
  if (t < nb) {
    int ex = sh[t] - orig;
    bbase[t] = ex;
    bcur[t] = ex;
    if (t == nb - 1) bbase[nb] = sh[t];
  }
}

__global__ __launch_bounds__(256) void k_bucket(const int* __restrict__ src,
                                                const int* __restrict__ dst, int e, int nb,
                                                int* __restrict__ bcur, uint* __restrict__ bpair) {
  __shared__ uint spair[CH];
  __shared__ ushort skey[CH];
  __shared__ ushort srank[CH];
  __shared__ int cnt[512];
  __shared__ int gb[512];
  int t = threadIdx.x;
  int c0 = blockIdx.x * CH;
  int cn = min(CH, e - c0);
  if (cn <= 0) return;
  for (int i = t; i < 512; i += 256) cnt[i] = 0;
  __syncthreads();
  for (int i = t; i < cn; i += 256) {
    int s = src[c0 + i];
    int d = dst[c0 + i];
    int k = d >> BSHIFT;
    spair[i] = ((uint)(d & ((1 << BSHIFT) - 1)) << 20) | (uint)s;
    skey[i] = (ushort)k;
    srank[i] = (ushort)atomicAdd(&cnt[k], 1);
  }
  __syncthreads();
  for (int k = t; k < nb; k += 256)
    gb[k] = cnt[k] ? atomicAdd(&bcur[k], cnt[k]) : 0;
  __syncthreads();
  for (int i = t; i < cn; i += 256) {
    bpair[gb[skey[i]] + srank[i]] = spair[i];
  }
}

__global__ __launch_bounds__(256) void k_csr(const uint* __restrict__ bpair,
                                             const int* __restrict__ bbase, int n,
                                             int* __restrict__ rowptr, int* __restrict__ col) {
  __shared__ int deg[256];
  __shared__ int cur[256];
  int b = blockIdx.x, t = threadIdx.x;
  int e0 = bbase[b], e1 = bbase[b + 1];
  deg[t] = 0;
  __syncthreads();
  for (int i = e0 + t; i < e1; i += 256)
    atomicAdd(&deg[bpair[i] >> 20], 1);
  __syncthreads();
  int v = deg[t];
  cur[t] = v;
  __syncthreads();
  for (int off = 1; off < 256; off <<= 1) {
    int u = (t >= off) ? cur[t - off] : 0;
    __syncthreads();
    cur[t] += u;
    __syncthreads();
  }
  int incl = cur[t];
  int gnode = b * 256 + t;
  if (gnode < n) rowptr[gnode + 1] = e0 + incl;
  if (b == 0 && t == 0) rowptr[0] = 0;
  __syncthreads();
  cur[t] = e0 + incl - v;
  __syncthreads();
  for (int i = e0 + t; i < e1; i += 256) {
    uint pk = bpair[i];
    int loc = pk >> 20;
    int p = atomicAdd(&cur[loc], 1);
    col[p] = (int)(pk & 0xFFFFFu);
  }
}

// ============================ weight prep ============================
__global__ void k_prep_vsd(const float* __restrict__ wsrc, const float* __restrict__ wdst,
                           const float* __restrict__ asrc, const float* __restrict__ adst,
                           float* __restrict__ vsd) {
  int k = blockIdx.x;
  int i = threadIdx.x;
  float s = 0.f;
  if (i < 8) {
    for (int c = 0; c < 16; ++c) s += wsrc[k * 128 + i * 16 + c] * asrc[i * 16 + c];
  } else {
    int h = i - 8;
    for (int c = 0; c < 16; ++c) s += wdst[k * 128 + h * 16 + c] * adst[h * 16 + c];
  }
  vsd[k * 16 + i] = s;
}

__global__ void k_prep_u3(const float* __restrict__ w3s, const float* __restrict__ w3d,
                          const float* __restrict__ a3s, const float* __restrict__ a3d,
                          float* __restrict__ U) {
  int k = blockIdx.x * blockDim.x + threadIdx.x;
  if (k >= 128) return;
  U[k * 4 + 0] = w3s[k * 2 + 0];
  U[k * 4 + 1] = w3s[k * 2 + 1];
  U[k * 4 + 2] = w3s[k * 2 + 0] * a3s[0] + w3s[k * 2 + 1] * a3s[1];
  U[k * 4 + 3] = w3d[k * 2 + 0] * a3d[0] + w3d[k * 2 + 1] * a3d[1];
}

// B-fragment pre-swizzle (see R6 notes)
__global__ __launch_bounds__(64) void k_prep_frag(const float* __restrict__ W,
                                                  const float* __restrict__ VSD,
                                                  ushort* __restrict__ WF) {
  int blk = blockIdx.x;  // ct*4+ks, 36 blocks
  int lane = threadIdx.x;
  int ct = blk >> 2, ks = blk & 3;
  uint out[4];
#pragma unroll
  for (int jj = 0; jj < 8; ++jj) {
    int k = ks * 32 + (lane >> 4) * 8 + jj;
    int c = ct * 16 + (lane & 15);
    float v = (c < 128) ? W[k * 128 + c] : VSD[k * 16 + (c - 128)];
    ((ushort*)out)[jj] = (ushort)f2bf(v);
  }
  *reinterpret_cast<uint4*>(&WF[(size_t)(blk * 64 + lane) * 8]) = *reinterpret_cast<uint4*>(out);
}

// ============================ MFMA GEMM: [XSb | AL] = Xtile @ [W | VSD] ============================
template <int INMODE>  // 0: fp32 X, 1: bf16 X
__global__ __launch_bounds__(256) void k_gemm_mfma(const void* __restrict__ Xv,
                                                   const ushort* __restrict__ WF,
                                                   ushort* __restrict__ XSb,
                                                   float* __restrict__ AL, int n) {
  __shared__ __align__(16) char xt[16384];  // 64 rows x 128 k bf16
  int t = threadIdx.x;
  int row0 = blockIdx.x * 64;

  if (INMODE == 0) {
    const float* X = (const float*)Xv;
#pragma unroll
    for (int i = 0; i < 8; ++i) {
      int flat = (i * 256 + t) * 4;
      int r = flat >> 7, k0 = flat & 127;
      int gr = row0 + r;
      float4 v = (gr < n) ? *reinterpret_cast<const float4*>(&X[(size_t)gr * 128 + k0])
                          : make_float4(0.f, 0.f, 0.f, 0.f);
      uint lo = f2bf(v.x) | (f2bf(v.y) << 16);
      uint hi = f2bf(v.z) | (f2bf(v.w) << 16);
      int byte = (r * 256 + k0 * 2) ^ ((r & 7) << 4);
      *reinterpret_cast<uint2*>(xt + byte) = make_uint2(lo, hi);
    }
  } else {
    const ushort* X = (const ushort*)Xv;
#pragma unroll
    for (int i = 0; i < 4; ++i) {
      int flat = (i * 256 + t) * 8;
      int r = flat >> 7, k0 = flat & 127;
      int gr = row0 + r;
      uint4 v = (gr < n) ? *reinterpret_cast<const uint4*>(&X[(size_t)gr * 128 + k0])
                         : make_uint4(0u, 0u, 0u, 0u);
      int byte = (r * 256 + k0 * 2) ^ ((r & 7) << 4);
      *reinterpret_cast<uint4*>(xt + byte) = v;
    }
  }
  __syncthreads();

  int wave = t >> 6;
  int lane = t & 63;
  int arow = wave * 16 + (lane & 15);
  int kgrp = (lane >> 4) * 8;

  bf16x8 afrag[4];
#pragma unroll
  for (int ks = 0; ks < 4; ++ks) {
    int kb = ks * 32 + kgrp;
    int byte = (arow * 256 + kb * 2) ^ ((arow & 7) << 4);
    afrag[ks] = *reinterpret_cast<const bf16x8*>(xt + byte);
  }

  f32x4 acc[9];
#pragma unroll
  for (int ct = 0; ct < 9; ++ct) {
    f32x4 a = {0.f, 0.f, 0.f, 0.f};
#pragma unroll
    for (int ks = 0; ks < 4; ++ks) {
      bf16x8 b = *reinterpret_cast<const bf16x8*>(&WF[(size_t)((ct * 4 + ks) * 64 + lane) * 8]);
      a = __builtin_amdgcn_mfma_f32_16x16x32_bf16(afrag[ks], b, a, 0, 0, 0);
    }
    acc[ct] = a;
  }

  int rbase = wave * 16 + (lane >> 4) * 4;
  int csub = lane & 15;
#pragma unroll
  for (int ct = 0; ct < 8; ++ct) {
#pragma unroll
    for (int i = 0; i < 4; ++i) {
      int gr = row0 + rbase + i;
      if (gr < n) XSb[(size_t)gr * 128 + ct * 16 + csub] = (ushort)f2bf(acc[ct][i]);
    }
  }
#pragma unroll
  for (int i = 0; i < 4; ++i) {
    int gr = row0 + rbase + i;
    if (gr < n) AL[(size_t)gr * 16 + csub] = acc[8][i];
  }
}

// ============================ layer 1/2 aggregation: 16-lane/edge, 4 edges/wave ============================
// lane: q = lane>>4 (edge group), sub = lane&15 (16B slice: channels 8*sub..8*sub+7, head sub>>1).
// Per round: group q handles edge base+q — 3 VMEM instrs per 4 edges. No LDS, no barriers.
// MODE 1: write bf16 activations HB. MODE 2: fused lin3 -> XSAL3[n][4] (needs U).
template <int MODE>
__global__ __launch_bounds__(256) void k_gat_agg(const ushort* __restrict__ XSb,
                                                 const float* __restrict__ AL,
                                                 const int* __restrict__ rowptr,
                                                 const int* __restrict__ col,
                                                 const float* __restrict__ bias,
                                                 void* __restrict__ OUTv,
                                                 const float* __restrict__ U, int n) {
  int t = threadIdx.x;
  int lane = t & 63;
  int node = blockIdx.x * 4 + (t >> 6);
  if (node >= n) return;
  int sub = lane & 15;
  int q = lane >> 4;
  uint hd4 = (uint)((sub >> 1) << 2);  // head byte offset in 64B AL row
  uint xoff = (uint)(sub * 16);        // byte offset in 256B XSb row
  const char* XB = (const char*)XSb;
  const char* AB = (const char*)AL;

  float ald = *(const float*)(AB + (((uint)node << 6) + 32u + hd4));

  // self loop: group 0 only
  float w0 = __expf(lrelu(*(const float*)(AB + (((uint)node << 6) + hd4)) + ald, LEAKY_ATT));
  if (q != 0) w0 = 0.f;
  uint4 qs = *(const uint4*)(XB + (((uint)node << 8) + xoff));
  float a0 = w0 * bf_lo(qs.x), a1 = w0 * bf_hi(qs.x);
  float a2 = w0 * bf_lo(qs.y), a3 = w0 * bf_hi(qs.y);
  float a4 = w0 * bf_lo(qs.z), a5 = w0 * bf_hi(qs.z);
  float a6 = w0 * bf_lo(qs.w), a7 = w0 * bf_hi(qs.w);
  float den = w0;

  int beg = rowptr[node], end = rowptr[node + 1];
  int base = beg;
  // main: 8 edges per iter (2 per group) — 6 VMEM instrs in flight
  for (; base + 8 <= end; base += 8) {
    int sA = col[base + q];
    int sB = col[base + 4 + q];
    float lA = *(const float*)(AB + (((uint)sA << 6) + hd4));
    float lB = *(const float*)(AB + (((uint)sB << 6) + hd4));
    uint4 qA = *(const uint4*)(XB + (((uint)sA << 8) + xoff));
    uint4 qB = *(const uint4*)(XB + (((uint)sB << 8) + xoff));
    float wA = __expf(lrelu(lA + ald, LEAKY_ATT));
    float wB = __expf(lrelu(lB + ald, LEAKY_ATT));
    a0 += wA * bf_lo(qA.x);
    a1 += wA * bf_hi(qA.x);
    a2 += wA * bf_lo(qA.y);
    a3 += wA * bf_hi(qA.y);
    a4 += wA * bf_lo(qA.z);
    a5 += wA * bf_hi(qA.z);
    a6 += wA * bf_lo(qA.w);
    a7 += wA * bf_hi(qA.w);
    a0 += wB * bf_lo(qB.x);
    a1 += wB * bf_hi(qB.x);
    a2 += wB * bf_lo(qB.y);
    a3 += wB * bf_hi(qB.y);
    a4 += wB * bf_lo(qB.z);
    a5 += wB * bf_hi(qB.z);
    a6 += wB * bf_lo(qB.w);
    a7 += wB * bf_hi(qB.w);
    den += wA + wB;
  }
  // masked rounds of 4 (0-7 edges left)
  for (; base < end; base += 4) {
    int idx = base + q;
    bool on = idx < end;
    int s = on ? col[idx] : node;
    float l = *(const float*)(AB + (((uint)s << 6) + hd4));
    uint4 qq = *(const uint4*)(XB + (((uint)s << 8) + xoff));
    float w = on ? __expf(lrelu(l + ald, LEAKY_ATT)) : 0.f;
    a0 += w * bf_lo(qq.x);
    a1 += w * bf_hi(qq.x);
    a2 += w * bf_lo(qq.y);
    a3 += w * bf_hi(qq.y);
    a4 += w * bf_lo(qq.z);
    a5 += w * bf_hi(qq.z);
    a6 += w * bf_lo(qq.w);
    a7 += w * bf_hi(qq.w);
    den += w;
  }

  // cross-group combine (4 groups: xor 16, 32)
  a0 += __shfl_xor(a0, 16);
  a1 += __shfl_xor(a1, 16);
  a2 += __shfl_xor(a2, 16);
  a3 += __shfl_xor(a3, 16);
  a4 += __shfl_xor(a4, 16);
  a5 += __shfl_xor(a5, 16);
  a6 += __shfl_xor(a6, 16);
  a7 += __shfl_xor(a7, 16);
  den += __shfl_xor(den, 16);
  a0 += __shfl_xor(a0, 32);
  a1 += __shfl_xor(a1, 32);
  a2 += __shfl_xor(a2, 32);
  a3 += __shfl_xor(a3, 32);
  a4 += __shfl_xor(a4, 32);
  a5 += __shfl_xor(a5, 32);
  a6 += __shfl_xor(a6, 32);
  a7 += __shfl_xor(a7, 32);
  den += __shfl_xor(den, 32);

  float inv = 1.f / den;
  int c0 = sub * 8;
  float4 bv0 = *reinterpret_cast<const float4*>(&bias[c0]);
  float4 bv1 = *reinterpret_cast<const float4*>(&bias[c0 + 4]);
  float r0 = lrelu(a0 * inv + bv0.x, LEAKY_ACT);
  float r1 = lrelu(a1 * inv + bv0.y, LEAKY_ACT);
  float r2 = lrelu(a2 * inv + bv0.z, LEAKY_ACT);
  float r3 = lrelu(a3 * inv + bv0.w, LEAKY_ACT);
  float r4 = lrelu(a4 * inv + bv1.x, LEAKY_ACT);
  float r5 = lrelu(a5 * inv + bv1.y, LEAKY_ACT);
  float r6 = lrelu(a6 * inv + bv1.z, LEAKY_ACT);
  float r7 = lrelu(a7 * inv + bv1.w, LEAKY_ACT);

  if (MODE == 1) {
    if (q == 0) {
      ushort* HB = (ushort*)OUTv;
      uint4 o;
      o.x = f2bf(r0) | (f2bf(r1) << 16);
      o.y = f2bf(r2) | (f2bf(r3) << 16);
      o.z = f2bf(r4) | (f2bf(r5) << 16);
      o.w = f2bf(r6) | (f2bf(r7) << 16);
      *reinterpret_cast<uint4*>(&HB[(size_t)node * 128 + c0]) = o;
    }
  } else {
    float rr[8] = {r0, r1, r2, r3, r4, r5, r6, r7};
    float p0 = 0.f, p1 = 0.f, p2 = 0.f, p3 = 0.f;
#pragma unroll
    for (int c = 0; c < 8; ++c) {
      float4 uv = *reinterpret_cast<const float4*>(&U[(c0 + c) * 4]);
      p0 += rr[c] * uv.x;
      p1 += rr[c] * uv.y;
      p2 += rr[c] * uv.z;
      p3 += rr[c] * uv.w;
    }
#pragma unroll
    for (int m = 1; m <= 8; m <<= 1) {
      p0 += __shfl_xor(p0, m);
      p1 += __shfl_xor(p1, m);
      p2 += __shfl_xor(p2, m);
      p3 += __shfl_xor(p3, m);
    }
    if (lane == 0) {
      float* X3 = (float*)OUTv;
      *reinterpret_cast<float4*>(&X3[(size_t)node * 4]) = make_float4(p0, p1, p2, p3);
    }
  }
}

// ============================ layer 3 aggregation: 4 edges in flight ============================
__global__ __launch_bounds__(256) void k_agg3(const float* __restrict__ XSAL3,
                                              const int* __restrict__ rowptr,
                                              const int* __restrict__ col,
                                              const float* __restrict__ b3,
                                              float* __restrict__ out, int n) {
  int node = blockIdx.x * blockDim.x + threadIdx.x;
  if (node >= n) return;
  const char* XB = (const char*)XSAL3;
  float4 self = *(const float4*)(XB + ((size_t)((uint)node << 4)));
  float ald = self.w;
  float w0 = __expf(lrelu(self.z + ald, LEAKY_ATT));
  float den = w0;
  float a0 = w0 * self.x;
  float a1 = w0 * self.y;
  int jj = rowptr[node], end = rowptr[node + 1];
  for (; jj + 4 <= end; jj += 4) {
    int sA = col[jj], sB = col[jj + 1], sC = col[jj + 2], sD = col[jj + 3];
    float4 vA = *(const float4*)(XB + ((uint)sA << 4));
    float4 vB = *(const float4*)(XB + ((uint)sB << 4));
    float4 vC = *(const float4*)(XB + ((uint)sC << 4));
    float4 vD = *(const float4*)(XB + ((uint)sD << 4));
    float wA = __expf(lrelu(vA.z + ald, LEAKY_ATT));
    float wB = __expf(lrelu(vB.z + ald, LEAKY_ATT));
    float wC = __expf(lrelu(vC.z + ald, LEAKY_ATT));
    float wD = __expf(lrelu(vD.z + ald, LEAKY_ATT));
    a0 += wA * vA.x + wB * vB.x + wC * vC.x + wD * vD.x;
    a1 += wA * vA.y + wB * vB.y + wC * vC.y + wD * vD.y;
    den += (wA + wB) + (wC + wD);
  }
  for (; jj < end; ++jj) {
    int s = col[jj];
    float4 v = *(const float4*)(XB + ((uint)s << 4));
    float w = __expf(lrelu(v.z + ald, LEAKY_ATT));
    den += w;
    a0 += w * v.x;
    a1 += w * v.y;
  }
  out[node * 2 + 0] = a0 / den + b3[0];
  out[node * 2 + 1] = a1 / den + b3[1];
}

// ============================ launch ============================
extern "C" void kernel_launch(void* const* d_in, const int* in_sizes, int n_in,
                              void* d_out, int out_size, void* d_ws, size_t ws_size,
                              hipStream_t stream) {
  const float* x = (const float*)d_in[0];
  const int* ei = (const int*)d_in[1];
  const float* w1s = (const float*)d_in[2];
  const float* w1d = (const float*)d_in[3];
  const float* a1s = (const float*)d_in[4];
  const float* a1d = (const float*)d_in[5];
  const float* b1 = (const float*)d_in[6];
  const float* w2s = (const float*)d_in[7];
  const float* w2d = (const float*)d_in[8];
  const float* a2s = (const float*)d_in[9];
  const float* a2d = (const float*)d_in[10];
  const float* b2 = (const float*)d_in[11];
  const float* w3s = (const float*)d_in[12];
  const float* w3d = (const float*)d_in[13];
  const float* a3s = (const float*)d_in[14];
  const float* a3d = (const float*)d_in[15];
  const float* b3 = (const float*)d_in[16];

  int n = in_sizes[0] / 128;
  int e = in_sizes[1] / 2;
  const int* srcp = ei;
  const int* dstp = ei + e;

  int nb = (n + 255) >> BSHIFT;
  if (nb > 512) return;
  if (n >= (1 << 20)) return;

  size_t off = 0;
  auto alloc = [&](size_t bytes) -> void* {
    void* p = (char*)d_ws + off;
    off += (bytes + 255) & ~(size_t)255;
    return p;
  };
  int* bcnt = (int*)alloc((size_t)nb * 4);
  int* bbase = (int*)alloc((size_t)(nb + 1) * 4);
  int* bcur = (int*)alloc((size_t)nb * 4);
  uint* bpair = (uint*)alloc((size_t)e * 4);
  int* rowptr = (int*)alloc((size_t)(n + 1) * 4);
  int* col = (int*)alloc((size_t)e * 4);
  float* vsd1 = (float*)alloc(128 * 16 * 4);
  float* vsd2 = (float*)alloc(128 * 16 * 4);
  float* u3 = (float*)alloc(128 * 4 * 4);
  ushort* wf1 = (ushort*)alloc(36 * 64 * 8 * 2);
  ushort* wf2 = (ushort*)alloc(36 * 64 * 8 * 2);
  float* al = (float*)alloc((size_t)n * 16 * 4);
  ushort* xsb = (ushort*)alloc((size_t)n * 128 * 2);
  ushort* hb = (ushort*)alloc((size_t)n * 128 * 2);
  float* xsal3 = (float*)alloc((size_t)n * 4 * 4);
  if (off > ws_size) return;

  // CSR build
  hipMemsetAsync(bcnt, 0, (size_t)nb * 4, stream);
  k_bhist<<<512, 256, 0, stream>>>(dstp, e, nb, bcnt);
  k_bscan<<<1, 512, 0, stream>>>(bcnt, nb, bbase, bcur);
  k_bucket<<<(e + CH - 1) / CH, 256, 0, stream>>>(srcp, dstp, e, nb, bcur, bpair);
  k_csr<<<nb, 256, 0, stream>>>(bpair, bbase, n, rowptr, col);

  // weight prep
  k_prep_vsd<<<128, 16, 0, stream>>>(w1s, w1d, a1s, a1d, vsd1);
  k_prep_vsd<<<128, 16, 0, stream>>>(w2s, w2d, a2s, a2d, vsd2);
  k_prep_u3<<<1, 128, 0, stream>>>(w3s, w3d, a3s, a3d, u3);
  k_prep_frag<<<36, 64, 0, stream>>>(w1s, vsd1, wf1);
  k_prep_frag<<<36, 64, 0, stream>>>(w2s, vsd2, wf2);

  int gb = (n + 63) / 64;
  int ab = (n + 3) / 4;
  // layer 1
  k_gemm_mfma<0><<<gb, 256, 0, stream>>>(x, wf1, xsb, al, n);
  k_gat_agg<1><<<ab, 256, 0, stream>>>(xsb, al, rowptr, col, b1, hb, nullptr, n);
  // layer 2 (+fused lin3)
  k_gemm_mfma<1><<<gb, 256, 0, stream>>>(hb, wf2, xsb, al, n);
  k_gat_agg<2><<<ab, 256, 0, stream>>>(xsb, al, rowptr, col, b2, xsal3, u3, n);
  // layer 3
  k_agg3<<<(n + 255) / 256, 256, 0, stream>>>(xsal3, rowptr, col, b3, (float*)d_out, n);
}